// Round 1
// baseline (247.461 us; speedup 1.0000x reference)
//
#include <hip/hip_runtime.h>

namespace {

typedef __attribute__((ext_vector_type(8)))  short          short8;
typedef __attribute__((ext_vector_type(8)))  unsigned short u16x8;
typedef __attribute__((ext_vector_type(4)))  unsigned short u16x4;
typedef __attribute__((ext_vector_type(4)))  float          f32x4;

constexpr int V   = 200;
constexpr int VP  = 208;   // v padded (13 x 16)
constexpr int UP  = 224;   // u padded (7 x 32)
constexpr int F   = 64;
constexpr int FO  = 64;
constexpr int NT  = 512;   // N*T

// Ac layout: u16 [NT][VP][7 kt][64] where per kt: cols 0..31 = A1, 32..63 = A2.
// Row stride 448 elems = 896 B; each (row,kt) pair is one 128B line (A1|A2).
constexpr int A_ROW = 448;

// ---- ws layout (bytes) ----
constexpr size_t WS_AC  = 0;            // ushort [512][208][448] = 95,420,416
constexpr size_t WS_D   = 95420416;     // float  [512][208] = 425,984 (atomic, memset 0)
constexpr size_t WS_SD  = 95846400;     // float  [512][208] = 425,984
constexpr size_t WS_AD  = 96272384;     // float  [8][224]   = 7,168
constexpr size_t WS_THT = 96279552;     // ushort [3][64][64] = 24,576   (end 96,304,128)

__device__ __forceinline__ unsigned short f2bf(float x) {
    union { float f; unsigned u; } c; c.f = x;
    unsigned r = c.u + 0x7FFF + ((c.u >> 16) & 1);
    return (unsigned short)(r >> 16);
}
__device__ __forceinline__ float bf2f(unsigned short h) {
    union { unsigned u; float f; } c; c.u = ((unsigned)h) << 16;
    return c.f;
}

// ============ P1: fused S_min + A1/A2 build + d (atomic) + sdiag ============
// grid (512, 28): pair p -> (ti <= tj) over the 7x7 tile grid. S read once.
// A1[v][u] = -min(S[v][u],S[u][v]) * Att[u][v]   (0 on diag u==v)
// A2[v][u] = 2*min^2 * Att[u][v]                 (0 on diag)
// written bf16 into Ac at both orientations; d row-sums via shuffle + atomicAdd.
__global__ __launch_bounds__(256)
void prep_A(const float* __restrict__ S,
            const float* __restrict__ Att,
            unsigned short* __restrict__ Ac,
            float* __restrict__ d_ws,
            float* __restrict__ sdiag)
{
    __shared__ float As[32][33];   // S  [ti-rows][tj-cols]
    __shared__ float Bs[32][33];   // S  [tj-rows][ti-cols]
    __shared__ float Ts[32][33];   // Att[ti-rows][tj-cols]
    __shared__ float Us[32][33];   // Att[tj-rows][ti-cols]

    const int b   = blockIdx.x;
    const int n   = b >> 6;
    const int tid = threadIdx.x;
    int rem = blockIdx.y, ti = 0;
    while (rem >= 7 - ti) { rem -= 7 - ti; ++ti; }
    const int tj = ti + rem;
    const bool diag = (ti == tj);

    const float* __restrict__ Sp = S   + (size_t)b * (V * V);
    const float* __restrict__ Ap = Att + (size_t)n * (V * V);

    const int r  = tid >> 3;      // 0..31
    const int cg = tid & 7;       // 0..7
    const int c0 = 4 * cg;

    {
        const int gr = 32 * ti + r, gc = 32 * tj + c0;
        float4 a = make_float4(0.f, 0.f, 0.f, 0.f);
        float4 t = make_float4(0.f, 0.f, 0.f, 0.f);
        if (gr < V && gc < V) {
            a = *(const float4*)&Sp[gr * V + gc];
            t = *(const float4*)&Ap[gr * V + gc];
        }
        As[r][c0 + 0] = a.x; As[r][c0 + 1] = a.y; As[r][c0 + 2] = a.z; As[r][c0 + 3] = a.w;
        Ts[r][c0 + 0] = t.x; Ts[r][c0 + 1] = t.y; Ts[r][c0 + 2] = t.z; Ts[r][c0 + 3] = t.w;
        if (!diag) {
            const int hr = 32 * tj + r, hc = 32 * ti + c0;
            float4 bb = make_float4(0.f, 0.f, 0.f, 0.f);
            float4 uu = make_float4(0.f, 0.f, 0.f, 0.f);
            if (hr < V && hc < V) {
                bb = *(const float4*)&Sp[hr * V + hc];
                uu = *(const float4*)&Ap[hr * V + hc];
            }
            Bs[r][c0 + 0] = bb.x; Bs[r][c0 + 1] = bb.y; Bs[r][c0 + 2] = bb.z; Bs[r][c0 + 3] = bb.w;
            Us[r][c0 + 0] = uu.x; Us[r][c0 + 1] = uu.y; Us[r][c0 + 2] = uu.z; Us[r][c0 + 3] = uu.w;
        }
    }
    __syncthreads();

    // ---- orientation 1: rows 32ti+r, kt = tj ----
    {
        const int vr = 32 * ti + r;
        float rs = 0.f;
        u16x4 w1, w2;
        #pragma unroll
        for (int e = 0; e < 4; ++e) {
            const int c = c0 + e;
            const float tw = diag ? As[c][r] : Bs[c][r];
            const float m  = fminf(As[r][c], tw);
            rs += m;
            const float att = diag ? Ts[c][r] : Us[c][r];   // Att[u][v]
            float a1 = -m * att;
            float a2 = 2.0f * m * m * att;
            if (diag && r == c) { a1 = 0.f; a2 = 0.f; }
            w1[e] = f2bf(a1); w2[e] = f2bf(a2);
        }
        float s = rs;
        s += __shfl_xor(s, 1); s += __shfl_xor(s, 2); s += __shfl_xor(s, 4);
        if (cg == 0 && vr < V)
            atomicAdd(&d_ws[b * VP + vr], s);
        if (diag && cg == 0 && vr < V)
            sdiag[b * VP + vr] = As[r][r];
        if (vr < VP) {
            const size_t base = ((size_t)(b * VP + vr) * 7 + tj) * 64;
            *(u16x4*)&Ac[base + c0]      = w1;
            *(u16x4*)&Ac[base + 32 + c0] = w2;
        }
    }

    // ---- mirror: rows 32tj+r, kt = ti (off-diag only) ----
    if (!diag) {
        const int vr2 = 32 * tj + r;
        float ts = 0.f;
        u16x4 w1, w2;
        #pragma unroll
        for (int e = 0; e < 4; ++e) {
            const int c = c0 + e;
            const float m = fminf(Bs[r][c], As[c][r]);
            ts += m;
            const float att = Ts[c][r];                     // Att[32ti+c][32tj+r]
            w1[e] = f2bf(-m * att);
            w2[e] = f2bf(2.0f * m * m * att);
        }
        float s = ts;
        s += __shfl_xor(s, 1); s += __shfl_xor(s, 2); s += __shfl_xor(s, 4);
        if (cg == 0 && vr2 < V)
            atomicAdd(&d_ws[b * VP + vr2], s);
        if (vr2 < VP) {
            const size_t base = ((size_t)(b * VP + vr2) * 7 + ti) * 64;
            *(u16x4*)&Ac[base + c0]      = w1;
            *(u16x4*)&Ac[base + 32 + c0] = w2;
        }
    }
}

// ============ P2: adiag[n][v] = Att[n][v][v] ============
__global__ __launch_bounds__(256)
void prep_adiag(const float* __restrict__ Att, float* __restrict__ adiag)
{
    const int n = blockIdx.x, tid = threadIdx.x;
    if (tid < UP)
        adiag[n * UP + tid] = (tid < V) ? Att[(size_t)n * (V * V) + tid * V + tid] : 0.f;
}

// ============ P3: ThT[k][fo][f] = bf16(Theta[k][f][fo]) ============
__global__ __launch_bounds__(256)
void prep_theta(const float* __restrict__ Theta,
                unsigned short* __restrict__ thT)
{
    __shared__ float T[64][65];
    const int k = blockIdx.x, tid = threadIdx.x;
    for (int idx = tid; idx < 4096; idx += 256)
        T[idx >> 6][idx & 63] = Theta[k * 4096 + idx];
    __syncthreads();
    for (int idx = tid; idx < 4096; idx += 256) {
        const int fo = idx >> 6, f = idx & 63;
        thT[k * 4096 + fo * 64 + f] = f2bf(T[f][fo]);
    }
}

// ============ G: barrier-free MFMA main loop + MFMA Theta epilogue ============
constexpr int XS_S = 68;   // xs (linear [u][f]) stride
constexpr int XT_S = 232;  // xsT (transposed [f][u]) stride
constexpr int YS_S = 72;   // ys / ThS stride

__global__ __launch_bounds__(256, 2)
void cheb_main(const float* __restrict__ x,
               const unsigned short* __restrict__ thT,
               const unsigned short* __restrict__ Ac,
               const float* __restrict__ d_ws,
               const float* __restrict__ sdiag,
               const float* __restrict__ adiag,
               float* __restrict__ out)
{
    __shared__ __align__(16) char smem[61824];
    unsigned short* xsT = (unsigned short*)smem;             // [64][232] = 29,696 (K loop)
    unsigned short* xs  = (unsigned short*)(smem + 29696);   // [224][68] = 30,464 (staging)
    unsigned short* ThS = (unsigned short*)smem;             // [64][72]  =  9,216 (epilogue)
    unsigned short* ys  = (unsigned short*)(smem + 29696);   // [208][72] = 29,952 (epilogue)
    float*        cbuf  = (float*)(smem + 60160);            // 832
    float*       adbuf  = (float*)(smem + 60992);            // 832 -> 61,824

    const int tid = threadIdx.x;
    const int b   = blockIdx.x;
    const int n   = b >> 6;
    const float* __restrict__ xp = x + (size_t)b * (V * F);
    const unsigned short* __restrict__ ap = Ac + (size_t)b * (VP * A_ROW);
    float* __restrict__ op = out + (size_t)b * (V * FO);

    // ---- phase A: stage x -> bf16 xs[u][f] (zeros for u >= 200), cbuf/adbuf ----
    for (int idx = tid; idx < UP * 16; idx += 256) {
        const int u = idx >> 4, fg = idx & 15;
        u16x4 w; w[0] = 0; w[1] = 0; w[2] = 0; w[3] = 0;
        if (u < V) {
            const float4 v = *(const float4*)&xp[u * F + 4 * fg];
            w[0] = f2bf(v.x); w[1] = f2bf(v.y); w[2] = f2bf(v.z); w[3] = f2bf(v.w);
        }
        *(u16x4*)&xs[u * XS_S + 4 * fg] = w;
    }
    if (tid < VP) {
        cbuf[tid]  = d_ws[b * VP + tid] - 1.0f - sdiag[b * VP + tid];  // c = d-1-S_vv
        adbuf[tid] = adiag[n * UP + tid];
    }
    __syncthreads();

    // ---- phase B: transpose xs -> xsT[f][u] (b128 writes, conflict-free) ----
    for (int it = 0; it < 7; ++it) {
        const int wid = tid + 256 * it;        // 0..1791
        const int f = wid & 63, uc = wid >> 6; // uc 0..27
        u16x8 w;
        #pragma unroll
        for (int j = 0; j < 8; ++j) w[j] = xs[(8 * uc + j) * XS_S + f];
        *(u16x8*)&xsT[f * XT_S + 8 * uc] = w;
    }
    __syncthreads();

    const int wave = tid >> 6, lane = tid & 63;
    const int q = lane >> 4, ln = lane & 15;
    const int myBase = (wave == 0) ? 0 : (4 + 3 * (wave - 1));
    const int myCnt  = (wave == 0) ? 4 : 3;

    f32x4 acc1[4][4], acc2[4][4];
    #pragma unroll
    for (int i = 0; i < 4; ++i)
        #pragma unroll
        for (int j = 0; j < 4; ++j) {
            acc1[i][j] = (f32x4)0.f; acc2[i][j] = (f32x4)0.f;
        }

    size_t rbase[4];
    #pragma unroll
    for (int vi = 0; vi < 4; ++vi)
        rbase[vi] = (size_t)((myBase + vi) * 16 + ln) * A_ROW;

    // ---- K loop: 7 steps of 32 u's, NO barriers. A-fragments stream from
    // global (double-buffered 1 kt ahead); B-fragments via ds_read_b128. ----
    short8 a1c[4] = {}, a2c[4] = {}, a1n[4] = {}, a2n[4] = {};
    #pragma unroll
    for (int vi = 0; vi < 4; ++vi) if (vi < myCnt) {
        a1c[vi] = *(const short8*)&ap[rbase[vi] + 8 * q];
        a2c[vi] = *(const short8*)&ap[rbase[vi] + 32 + 8 * q];
    }
    #pragma unroll 1
    for (int kt = 0; kt < 7; ++kt) {
        if (kt < 6) {
            #pragma unroll
            for (int vi = 0; vi < 4; ++vi) if (vi < myCnt) {
                a1n[vi] = *(const short8*)&ap[rbase[vi] + (kt + 1) * 64 + 8 * q];
                a2n[vi] = *(const short8*)&ap[rbase[vi] + (kt + 1) * 64 + 32 + 8 * q];
            }
        }
        short8 bfr[4];
        #pragma unroll
        for (int ft = 0; ft < 4; ++ft)
            bfr[ft] = *(const short8*)&xsT[(16 * ft + ln) * XT_S + 32 * kt + 8 * q];
        #pragma unroll
        for (int vi = 0; vi < 4; ++vi) if (vi < myCnt) {
            #pragma unroll
            for (int ft = 0; ft < 4; ++ft) {
                acc1[vi][ft] = __builtin_amdgcn_mfma_f32_16x16x32_bf16(a1c[vi], bfr[ft], acc1[vi][ft], 0, 0, 0);
                acc2[vi][ft] = __builtin_amdgcn_mfma_f32_16x16x32_bf16(a2c[vi], bfr[ft], acc2[vi][ft], 0, 0, 0);
            }
        }
        #pragma unroll
        for (int vi = 0; vi < 4; ++vi) { a1c[vi] = a1n[vi]; a2c[vi] = a2n[vi]; }
    }

    // ---- epilogue: out-tiles += mfma(ys_k, ThT_k) for k = 1, 2, 0 ----
    f32x4 ot[4][4];
    #pragma unroll
    for (int i = 0; i < 4; ++i)
        #pragma unroll
        for (int j = 0; j < 4; ++j) ot[i][j] = (f32x4)0.f;

    #pragma unroll
    for (int pass = 0; pass < 3; ++pass) {
        const int k = (pass == 0) ? 1 : (pass == 1) ? 2 : 0;
        __syncthreads();   // K-loop xsT reads / prev pass MFMA reads done

        if (k == 0) {
            for (int idx = tid; idx < VP * 16; idx += 256) {
                const int v = idx >> 4, fg = idx & 15;
                u16x4 w; w[0] = 0; w[1] = 0; w[2] = 0; w[3] = 0;
                if (v < V) {
                    const float av = adbuf[v];
                    const float4 xv = *(const float4*)&xp[v * F + 4 * fg];
                    w[0] = f2bf(av * xv.x); w[1] = f2bf(av * xv.y);
                    w[2] = f2bf(av * xv.z); w[3] = f2bf(av * xv.w);
                }
                *(u16x4*)&ys[v * YS_S + 4 * fg] = w;
            }
        } else {
            #pragma unroll
            for (int vi = 0; vi < 4; ++vi) {
                if (vi < myCnt) {
                    const int vt = myBase + vi;
                    #pragma unroll
                    for (int ft = 0; ft < 4; ++ft) {
                        const f32x4 a = (k == 1) ? acc1[vi][ft] : acc2[vi][ft];
                        #pragma unroll
                        for (int reg = 0; reg < 4; ++reg) {
                            const int v = vt * 16 + 4 * q + reg;
                            float val = 0.f;
                            if (v < V) {
                                const float cc = cbuf[v];
                                const float dc = ((k == 1) ? cc : (2.0f * cc * cc - 1.0f)) * adbuf[v];
                                val = a[reg] + dc * xp[v * F + 16 * ft + ln];
                            }
                            ys[v * YS_S + 16 * ft + ln] = f2bf(val);
                        }
                    }
                }
            }
        }
        for (int idx = tid; idx < 64 * 8; idx += 256) {
            const int fo = idx >> 3, ch = idx & 7;
            *(u16x8*)&ThS[fo * YS_S + 8 * ch] =
                *(const u16x8*)&thT[k * 4096 + fo * 64 + 8 * ch];
        }
        __syncthreads();
        #pragma unroll
        for (int vi = 0; vi < 4; ++vi) {
            if (vi < myCnt) {
                const int vrow = (myBase + vi) * 16 + ln;
                #pragma unroll
                for (int ks = 0; ks < 2; ++ks) {
                    const short8 af = *(const short8*)&ys[vrow * YS_S + 32 * ks + 8 * q];
                    #pragma unroll
                    for (int fot = 0; fot < 4; ++fot) {
                        const short8 bf = *(const short8*)&ThS[(16 * fot + ln) * YS_S + 32 * ks + 8 * q];
                        ot[vi][fot] = __builtin_amdgcn_mfma_f32_16x16x32_bf16(af, bf, ot[vi][fot], 0, 0, 0);
                    }
                }
            }
        }
    }

    // ---- relu + store (C-layout: row v = 4q+reg, col fo = ln) ----
    #pragma unroll
    for (int vi = 0; vi < 4; ++vi) {
        if (vi < myCnt) {
            const int vt = myBase + vi;
            #pragma unroll
            for (int fot = 0; fot < 4; ++fot) {
                #pragma unroll
                for (int reg = 0; reg < 4; ++reg) {
                    const int v = vt * 16 + 4 * q + reg;
                    if (v < V)
                        op[v * FO + 16 * fot + ln] = fmaxf(ot[vi][fot][reg], 0.f);
                }
            }
        }
    }
}

} // namespace

extern "C" void kernel_launch(void* const* d_in, const int* in_sizes, int n_in,
                              void* d_out, int out_size, void* d_ws, size_t ws_size,
                              hipStream_t stream) {
    const float* x     = (const float*)d_in[0];
    const float* Att   = (const float*)d_in[1];
    const float* S     = (const float*)d_in[2];
    const float* Theta = (const float*)d_in[3];
    float* out         = (float*)d_out;

    char* ws = (char*)d_ws;
    unsigned short* Ac  = (unsigned short*)(ws + WS_AC);
    float* d_sum        = (float*)(ws + WS_D);
    float* sdiag        = (float*)(ws + WS_SD);
    float* adiag        = (float*)(ws + WS_AD);
    unsigned short* thT = (unsigned short*)(ws + WS_THT);

    // d accumulates via atomicAdd -> must start at 0 every call
    hipMemsetAsync(d_sum, 0, (size_t)NT * VP * sizeof(float), stream);

    hipLaunchKernelGGL(prep_A,     dim3(NT, 28), dim3(256), 0, stream, S, Att, Ac, d_sum, sdiag);
    hipLaunchKernelGGL(prep_adiag, dim3(8),      dim3(256), 0, stream, Att, adiag);
    hipLaunchKernelGGL(prep_theta, dim3(3),      dim3(256), 0, stream, Theta, thT);
    hipLaunchKernelGGL(cheb_main,  dim3(NT),     dim3(256), 0, stream,
                       x, thT, Ac, d_sum, sdiag, adiag, out);
}